// Round 13
// baseline (74.380 us; speedup 1.0000x reference)
//
#include <hip/hip_runtime.h>
#include <hip/hip_bf16.h>

#define F 64
#define C 128
#define SPAN 64           // rows per wave
#define NT (SPAN / 16)    // 4 sixteen-row MFMA tiles per wave

typedef __attribute__((ext_vector_type(8))) short short8;
typedef __attribute__((ext_vector_type(4))) float floatx4;

__device__ __forceinline__ unsigned short f32_to_bf16_rne(float f) {
    unsigned int u = __builtin_bit_cast(unsigned int, f);
    unsigned int r = u + 0x7FFFu + ((u >> 16) & 1u);
    return (unsigned short)(r >> 16);
}

// compiler lowers pairs of these to v_cvt_pk_bf16_f32 (m240)
__device__ __forceinline__ short bf16c(float f) {
    return __builtin_bit_cast(short, __float2bfloat16(f));
}

// W is pre-scaled by -log2(e) in prep, so acc = -v*log2e and
// sigmoid(v) = rcp(1 + exp2(acc)) — no per-value multiply.
__device__ __forceinline__ float sig_from_scaled(float acc) {
    return __builtin_amdgcn_rcpf(1.0f + __builtin_amdgcn_exp2f(acc));
}

// Zero d_out (blocks 0..Z-1); build per-lane bf16 W fragments in d_ws
// (last 4 blocks). Entry idx = (nf*2+ks)*64 + lane, 8 bf16 each;
// col = nf*16+(lane&15), k = ks*32 + (lane>>4)*8 + e. W scaled by -log2(e).
__global__ __launch_bounds__(256) void prep_kernel(
    const float* __restrict__ w, float* __restrict__ out,
    unsigned short* __restrict__ wsfrag, int out_f4, int zblocks)
{
    const int b = blockIdx.x;
    if (b < zblocks) {
        int idx = b * 256 + threadIdx.x;
        if (idx < out_f4) ((float4*)out)[idx] = make_float4(0.f, 0.f, 0.f, 0.f);
    } else {
        int idx = (b - zblocks) * 256 + threadIdx.x;  // 0..1023
        int lane = idx & 63;
        int ks   = (idx >> 6) & 1;
        int nf   = idx >> 7;                          // 0..7
        int col  = nf * 16 + (lane & 15);
        int kg   = (lane >> 4) * 8;
        unsigned short* dst = wsfrag + (size_t)idx * 8;
        #pragma unroll
        for (int e = 0; e < 8; ++e) {
            int k = ks * 32 + kg + e;
            dst[e] = f32_to_bf16_rne(w[k * C + col] * -1.44269504088896f);
        }
    }
}

// R11 structure verbatim (62.1 us), ONLY change: nontemporal loads on the
// x stream (and seg) — x is 256MB single-touch; keep it from evicting the
// reused lines (W-frags, out atomic lines) in L2/L3. (R12 fix: nontemporal
// builtin needs ext_vector type, not HIP_vector_type struct — use floatx4.)
// SESSION RULES: (256,4) = spill poison (R5/R7/R9); prefetch depth, span,
// prep parallelism all measured neutral (R8/R10/R11).
__global__ __launch_bounds__(256, 3) void fused_seg_gemm(
    const float* __restrict__ x, const unsigned short* __restrict__ wsfrag,
    const int* __restrict__ seg, float* __restrict__ out)
{
    __shared__ unsigned short wlds[16 * 64 * 8];     // 16 KB: [(nf*2+ks)*64+lane]*8

    const int tid  = threadIdx.x;
    const int lane = tid & 63;
    const int wave = tid >> 6;
    const int l15  = lane & 15;
    const int g    = lane >> 4;
    const long long base = ((long long)blockIdx.x * 4 + wave) * SPAN;

    // ---- stage W frags to LDS: 1024 x 16B, coalesced, once per block ----
    {
        const short8* fb = (const short8*)wsfrag;
        short8* fl = (short8*)wlds;
        #pragma unroll
        for (int i = 0; i < 4; ++i) fl[tid + i * 256] = fb[tid + i * 256];
    }

    // seg for the wave's 64-row span: 1 reg, extracted per tile by shuffle
    int sg0 = __builtin_nontemporal_load(&seg[base + lane]);

    const floatx4* xp = (const floatx4*)(x + base * F);
    const int fi = l15 * 16 + g * 2;   // A-frag float4 index (+1 hi, +8 ks1)

    float runsum[8];
    #pragma unroll
    for (int nf = 0; nf < 8; ++nf) runsum[nf] = 0.0f;
    int cur_seg = -1;

    auto flush = [&]() {
        if (cur_seg >= 0) {
            #pragma unroll
            for (int nf = 0; nf < 8; ++nf) {
                float v = runsum[nf];
                v += __shfl_xor(v, 16);
                v += __shfl_xor(v, 32);
                if (lane < 16) atomicAdd(&out[cur_seg * C + nf * 16 + lane], v);
                runsum[nf] = 0.0f;
            }
        }
        cur_seg = -1;
    };

    floatx4 bufA0, bufA1, bufA2, bufA3;   // named scalars: never address-taken
    floatx4 bufB0, bufB1, bufB2, bufB3;

#define ISSUE(B0, B1, B2, B3, T) { const int o_ = fi + (T) * 256; \
        B0 = __builtin_nontemporal_load(&xp[o_]); \
        B1 = __builtin_nontemporal_load(&xp[o_ + 1]); \
        B2 = __builtin_nontemporal_load(&xp[o_ + 8]); \
        B3 = __builtin_nontemporal_load(&xp[o_ + 9]); }

#define STEP(B0, B1, B2, B3, T) { \
        short8 a0, a1; \
        a0[0] = bf16c(B0[0]); a0[1] = bf16c(B0[1]); a0[2] = bf16c(B0[2]); a0[3] = bf16c(B0[3]); \
        a0[4] = bf16c(B1[0]); a0[5] = bf16c(B1[1]); a0[6] = bf16c(B1[2]); a0[7] = bf16c(B1[3]); \
        a1[0] = bf16c(B2[0]); a1[1] = bf16c(B2[1]); a1[2] = bf16c(B2[2]); a1[3] = bf16c(B2[3]); \
        a1[4] = bf16c(B3[0]); a1[5] = bf16c(B3[1]); a1[6] = bf16c(B3[2]); a1[7] = bf16c(B3[3]); \
        if ((T) + 2 < NT) ISSUE(B0, B1, B2, B3, (T) + 2)  /* depth-2 prefetch */ \
        const short8* bl_ = (const short8*)wlds; \
        floatx4 acc[8]; \
        _Pragma("unroll") \
        for (int nf = 0; nf < 8; ++nf) { \
            short8 b0 = bl_[(nf * 2 + 0) * 64 + lane]; \
            short8 b1 = bl_[(nf * 2 + 1) * 64 + lane]; \
            acc[nf] = (floatx4)0.0f; \
            acc[nf] = __builtin_amdgcn_mfma_f32_16x16x32_bf16(a0, b0, acc[nf], 0, 0, 0); \
            acc[nf] = __builtin_amdgcn_mfma_f32_16x16x32_bf16(a1, b1, acc[nf], 0, 0, 0); \
        } \
        /* C/D (m89): col = nf*16 + l15, tile-row = g*4 + r */ \
        const int tb = (T) * 16; \
        const int u0 = __shfl(sg0, tb), u15 = __shfl(sg0, tb + 15); \
        if (u0 == u15) {                       /* uniform tile (~94%) */ \
            if (u0 != cur_seg) { flush(); cur_seg = u0; } \
            _Pragma("unroll") \
            for (int nf = 0; nf < 8; ++nf) \
                _Pragma("unroll") \
                for (int r = 0; r < 4; ++r) \
                    runsum[nf] += sig_from_scaled(acc[nf][r]); \
        } else {                               /* boundary tile: monotone walk */ \
            flush(); \
            const int sr0 = __shfl(sg0, tb + g * 4 + 0), sr1 = __shfl(sg0, tb + g * 4 + 1); \
            const int sr2 = __shfl(sg0, tb + g * 4 + 2), sr3 = __shfl(sg0, tb + g * 4 + 3); \
            _Pragma("unroll") \
            for (int nf = 0; nf < 8; ++nf) { \
                const int col = nf * 16 + l15; \
                float run = sig_from_scaled(acc[nf][0]); \
                int   rs  = sr0; \
                float v; \
                v = sig_from_scaled(acc[nf][1]); \
                if (sr1 != rs) { atomicAdd(&out[rs * C + col], run); rs = sr1; run = v; } else run += v; \
                v = sig_from_scaled(acc[nf][2]); \
                if (sr2 != rs) { atomicAdd(&out[rs * C + col], run); rs = sr2; run = v; } else run += v; \
                v = sig_from_scaled(acc[nf][3]); \
                if (sr3 != rs) { atomicAdd(&out[rs * C + col], run); rs = sr3; run = v; } else run += v; \
                atomicAdd(&out[rs * C + col], run); \
            } \
        } \
    }

    ISSUE(bufA0, bufA1, bufA2, bufA3, 0)
    ISSUE(bufB0, bufB1, bufB2, bufB3, 1)
    __syncthreads();   // W staged (x loads for tiles 0,1 already in flight)

    STEP(bufA0, bufA1, bufA2, bufA3, 0)
    STEP(bufB0, bufB1, bufB2, bufB3, 1)
    STEP(bufA0, bufA1, bufA2, bufA3, 2)
    STEP(bufB0, bufB1, bufB2, bufB3, 3)
    flush();
#undef ISSUE
#undef STEP
}

extern "C" void kernel_launch(void* const* d_in, const int* in_sizes, int n_in,
                              void* d_out, int out_size, void* d_ws, size_t ws_size,
                              hipStream_t stream) {
    const float* x  = (const float*)d_in[0];
    const float* w  = (const float*)d_in[1];
    const int* seg  = (const int*)d_in[2];
    float* out      = (float*)d_out;

    const int n = in_sizes[0] / F;                    // 1048576
    const int nblocks = n / (4 * SPAN);               // 4096 blocks x 4 waves x 64 rows

    const int out_f4 = out_size / 4;
    const int zblocks = (out_f4 + 255) / 256;

    prep_kernel<<<zblocks + 4, 256, 0, stream>>>(
        w, out, (unsigned short*)d_ws, out_f4, zblocks);

    fused_seg_gemm<<<nblocks, 256, 0, stream>>>(
        x, (const unsigned short*)d_ws, seg, out);
}

// Round 14
// 61.824 us; speedup vs baseline: 1.2031x; 1.2031x over previous
//
#include <hip/hip_runtime.h>
#include <hip/hip_bf16.h>

#define F 64
#define C 128
#define SPAN 64           // rows per wave
#define NT (SPAN / 16)    // 4 sixteen-row MFMA tiles per wave

typedef __attribute__((ext_vector_type(8))) short short8;
typedef __attribute__((ext_vector_type(4))) float floatx4;

__device__ __forceinline__ unsigned short f32_to_bf16_rne(float f) {
    unsigned int u = __builtin_bit_cast(unsigned int, f);
    unsigned int r = u + 0x7FFFu + ((u >> 16) & 1u);
    return (unsigned short)(r >> 16);
}

// compiler lowers pairs of these to v_cvt_pk_bf16_f32 (m240)
__device__ __forceinline__ short bf16c(float f) {
    return __builtin_bit_cast(short, __float2bfloat16(f));
}

// W is pre-scaled by -log2(e) in prep, so acc = -v*log2e and
// sigmoid(v) = rcp(1 + exp2(acc)) — no per-value multiply.
__device__ __forceinline__ float sig_from_scaled(float acc) {
    return __builtin_amdgcn_rcpf(1.0f + __builtin_amdgcn_exp2f(acc));
}

// Zero d_out (blocks 0..Z-1); build per-lane bf16 W fragments in d_ws
// (last 4 blocks). Entry idx = (nf*2+ks)*64 + lane, 8 bf16 each;
// col = nf*16+(lane&15), k = ks*32 + (lane>>4)*8 + e. W scaled by -log2(e).
__global__ __launch_bounds__(256) void prep_kernel(
    const float* __restrict__ w, float* __restrict__ out,
    unsigned short* __restrict__ wsfrag, int out_f4, int zblocks)
{
    const int b = blockIdx.x;
    if (b < zblocks) {
        int idx = b * 256 + threadIdx.x;
        if (idx < out_f4) ((float4*)out)[idx] = make_float4(0.f, 0.f, 0.f, 0.f);
    } else {
        int idx = (b - zblocks) * 256 + threadIdx.x;  // 0..1023
        int lane = idx & 63;
        int ks   = (idx >> 6) & 1;
        int nf   = idx >> 7;                          // 0..7
        int col  = nf * 16 + (lane & 15);
        int kg   = (lane >> 4) * 8;
        unsigned short* dst = wsfrag + (size_t)idx * 8;
        #pragma unroll
        for (int e = 0; e < 8; ++e) {
            int k = ks * 32 + kg + e;
            dst[e] = f32_to_bf16_rne(w[k * C + col] * -1.44269504088896f);
        }
    }
}

// FINAL (R11 verbatim, 62.1 us proven — best of session).
// Structure: LDS-free X path; each wave streams 64 rows as 4 sixteen-row
// MFMA tiles, A-fragments loaded straight from global (wave's 64x16B =
// contiguous 4KB), depth-2 prefetch via named register buffers; W bf16
// fragments in LDS (16KB, lane-contiguous conflict-free ds_read_b128);
// per-column bag sums carried in registers, flushed via shfl+atomicAdd at
// segment boundaries only.
// SESSION LEDGER: (256,4) = spill poison (R5:131 R7:128 R9:98 us);
// prefetch depth (R8), prep parallelism+prescale (R10), span/drain (R11)
// all neutral; nontemporal x loads (R13: 74 us) NEGATIVE — x line-reuse in
// L2 is real and must stay cached. ~72% of copy ceiling = structure's limit.
__global__ __launch_bounds__(256, 3) void fused_seg_gemm(
    const float* __restrict__ x, const unsigned short* __restrict__ wsfrag,
    const int* __restrict__ seg, float* __restrict__ out)
{
    __shared__ unsigned short wlds[16 * 64 * 8];     // 16 KB: [(nf*2+ks)*64+lane]*8

    const int tid  = threadIdx.x;
    const int lane = tid & 63;
    const int wave = tid >> 6;
    const int l15  = lane & 15;
    const int g    = lane >> 4;
    const long long base = ((long long)blockIdx.x * 4 + wave) * SPAN;

    // ---- stage W frags to LDS: 1024 x 16B, coalesced, once per block ----
    {
        const short8* fb = (const short8*)wsfrag;
        short8* fl = (short8*)wlds;
        #pragma unroll
        for (int i = 0; i < 4; ++i) fl[tid + i * 256] = fb[tid + i * 256];
    }

    // seg for the wave's 64-row span: 1 reg, extracted per tile by shuffle
    int sg0 = seg[base + lane];

    const float4* xp = (const float4*)(x + base * F);
    const int fi = l15 * 16 + g * 2;   // A-frag float4 index (+1 hi, +8 ks1)

    float runsum[8];
    #pragma unroll
    for (int nf = 0; nf < 8; ++nf) runsum[nf] = 0.0f;
    int cur_seg = -1;

    auto flush = [&]() {
        if (cur_seg >= 0) {
            #pragma unroll
            for (int nf = 0; nf < 8; ++nf) {
                float v = runsum[nf];
                v += __shfl_xor(v, 16);
                v += __shfl_xor(v, 32);
                if (lane < 16) atomicAdd(&out[cur_seg * C + nf * 16 + lane], v);
                runsum[nf] = 0.0f;
            }
        }
        cur_seg = -1;
    };

    float4 bufA0, bufA1, bufA2, bufA3;   // named scalars: never address-taken
    float4 bufB0, bufB1, bufB2, bufB3;

#define ISSUE(B0, B1, B2, B3, T) { const int o_ = fi + (T) * 256; \
        B0 = xp[o_]; B1 = xp[o_ + 1]; B2 = xp[o_ + 8]; B3 = xp[o_ + 9]; }

#define STEP(B0, B1, B2, B3, T) { \
        short8 a0, a1; \
        a0[0] = bf16c(B0.x); a0[1] = bf16c(B0.y); a0[2] = bf16c(B0.z); a0[3] = bf16c(B0.w); \
        a0[4] = bf16c(B1.x); a0[5] = bf16c(B1.y); a0[6] = bf16c(B1.z); a0[7] = bf16c(B1.w); \
        a1[0] = bf16c(B2.x); a1[1] = bf16c(B2.y); a1[2] = bf16c(B2.z); a1[3] = bf16c(B2.w); \
        a1[4] = bf16c(B3.x); a1[5] = bf16c(B3.y); a1[6] = bf16c(B3.z); a1[7] = bf16c(B3.w); \
        if ((T) + 2 < NT) ISSUE(B0, B1, B2, B3, (T) + 2)  /* depth-2 prefetch */ \
        const short8* bl_ = (const short8*)wlds; \
        floatx4 acc[8]; \
        _Pragma("unroll") \
        for (int nf = 0; nf < 8; ++nf) { \
            short8 b0 = bl_[(nf * 2 + 0) * 64 + lane]; \
            short8 b1 = bl_[(nf * 2 + 1) * 64 + lane]; \
            acc[nf] = (floatx4)0.0f; \
            acc[nf] = __builtin_amdgcn_mfma_f32_16x16x32_bf16(a0, b0, acc[nf], 0, 0, 0); \
            acc[nf] = __builtin_amdgcn_mfma_f32_16x16x32_bf16(a1, b1, acc[nf], 0, 0, 0); \
        } \
        /* C/D (m89): col = nf*16 + l15, tile-row = g*4 + r */ \
        const int tb = (T) * 16; \
        const int u0 = __shfl(sg0, tb), u15 = __shfl(sg0, tb + 15); \
        if (u0 == u15) {                       /* uniform tile (~94%) */ \
            if (u0 != cur_seg) { flush(); cur_seg = u0; } \
            _Pragma("unroll") \
            for (int nf = 0; nf < 8; ++nf) \
                _Pragma("unroll") \
                for (int r = 0; r < 4; ++r) \
                    runsum[nf] += sig_from_scaled(acc[nf][r]); \
        } else {                               /* boundary tile: monotone walk */ \
            flush(); \
            const int sr0 = __shfl(sg0, tb + g * 4 + 0), sr1 = __shfl(sg0, tb + g * 4 + 1); \
            const int sr2 = __shfl(sg0, tb + g * 4 + 2), sr3 = __shfl(sg0, tb + g * 4 + 3); \
            _Pragma("unroll") \
            for (int nf = 0; nf < 8; ++nf) { \
                const int col = nf * 16 + l15; \
                float run = sig_from_scaled(acc[nf][0]); \
                int   rs  = sr0; \
                float v; \
                v = sig_from_scaled(acc[nf][1]); \
                if (sr1 != rs) { atomicAdd(&out[rs * C + col], run); rs = sr1; run = v; } else run += v; \
                v = sig_from_scaled(acc[nf][2]); \
                if (sr2 != rs) { atomicAdd(&out[rs * C + col], run); rs = sr2; run = v; } else run += v; \
                v = sig_from_scaled(acc[nf][3]); \
                if (sr3 != rs) { atomicAdd(&out[rs * C + col], run); rs = sr3; run = v; } else run += v; \
                atomicAdd(&out[rs * C + col], run); \
            } \
        } \
    }

    ISSUE(bufA0, bufA1, bufA2, bufA3, 0)
    ISSUE(bufB0, bufB1, bufB2, bufB3, 1)
    __syncthreads();   // W staged (x loads for tiles 0,1 already in flight)

    STEP(bufA0, bufA1, bufA2, bufA3, 0)
    STEP(bufB0, bufB1, bufB2, bufB3, 1)
    STEP(bufA0, bufA1, bufA2, bufA3, 2)
    STEP(bufB0, bufB1, bufB2, bufB3, 3)
    flush();
#undef ISSUE
#undef STEP
}

extern "C" void kernel_launch(void* const* d_in, const int* in_sizes, int n_in,
                              void* d_out, int out_size, void* d_ws, size_t ws_size,
                              hipStream_t stream) {
    const float* x  = (const float*)d_in[0];
    const float* w  = (const float*)d_in[1];
    const int* seg  = (const int*)d_in[2];
    float* out      = (float*)d_out;

    const int n = in_sizes[0] / F;                    // 1048576
    const int nblocks = n / (4 * SPAN);               // 4096 blocks x 4 waves x 64 rows

    const int out_f4 = out_size / 4;
    const int zblocks = (out_f4 + 255) / 256;

    prep_kernel<<<zblocks + 4, 256, 0, stream>>>(
        w, out, (unsigned short*)d_ws, out_f4, zblocks);

    fused_seg_gemm<<<nblocks, 256, 0, stream>>>(
        x, (const unsigned short*)d_ws, seg, out);
}